// Round 10
// baseline (276.165 us; speedup 1.0000x reference)
//
#include <hip/hip_runtime.h>
#include <stdint.h>

// Problem constants (fixed by reference setup_inputs)
#define NTOK   8192
#define NEXP   64
#define HID    4096
#define TOPK   8
#define OUTROW 65536   // NTOK * TOPK
#define CHUNK  256     // tokens per chunk
#define NCHUNK 32      // NTOK / CHUNK
#define NPART  2048    // NEXP * NCHUNK, expert-major chunk-minor

typedef float f32x4 __attribute__((ext_vector_type(4)));
typedef unsigned long long u64;

// ---------------------------------------------------------------------------
// K1: per-token expert bitmasks + per-(expert,chunk) counts.
// 32 blocks x 256 threads (one block per token chunk) — map read exactly once
// (2 MB, coalesced: lane = expert).
__global__ void mask_count_kernel(const int* __restrict__ map,
                                  u64* __restrict__ masks,
                                  int* __restrict__ pcnt) {
    int c = blockIdx.x;
    int tid = threadIdx.x;
    int w = tid >> 6, lane = tid & 63;

    __shared__ u64 sm[CHUNK];
    __shared__ int hcnt[NEXP];
    if (tid < NEXP) hcnt[tid] = 0;

    int t0 = c * CHUNK + w * 64;
#pragma unroll 8
    for (int i = 0; i < 64; ++i) {
        int v = map[(size_t)(t0 + i) * NEXP + lane];   // coalesced: lane = expert
        u64 bal = __ballot(v != 0);
        if (lane == 0) sm[w * 64 + i] = bal;
    }
    __syncthreads();

    u64 mk = sm[tid];
    masks[c * CHUNK + tid] = mk;                       // global token id = c*256+tid
    while (mk) {
        int e = __ffsll((long long)mk) - 1;
        atomicAdd(&hcnt[e], 1);
        mk &= mk - 1;
    }
    __syncthreads();
    if (tid < NEXP) pcnt[tid * NCHUNK + c] = hcnt[tid]; // flat [e][c] layout
}

// ---------------------------------------------------------------------------
// K2: exclusive prefix over the 2048 flat (expert-major, chunk-minor) counts.
// One block, 256 threads, 8 values/thread.
__global__ void scan_kernel(const int* __restrict__ pcnt, int* __restrict__ poffs) {
    __shared__ int s[256];
    int tid = threadIdx.x;
    int v[8];
    int sum = 0;
#pragma unroll
    for (int i = 0; i < 8; ++i) { v[i] = pcnt[tid * 8 + i]; sum += v[i]; }
    s[tid] = sum;
    __syncthreads();
    for (int off = 1; off < 256; off <<= 1) {
        int x = (tid >= off) ? s[tid - off] : 0;
        __syncthreads();
        s[tid] += x;
        __syncthreads();
    }
    int base = (tid == 0) ? 0 : s[tid - 1];  // exclusive
#pragma unroll
    for (int i = 0; i < 8; ++i) { poffs[tid * 8 + i] = base; base += v[i]; }
}

// ---------------------------------------------------------------------------
// K3 (mega): one block per token. Computes the token's 8 output positions
// in-kernel (poffs lookup + packed-u64 rank reduction), writes probs/idx for
// its 8 entries, then streams the 16 KB row.
// A/B this round: PLAIN stores (fills demonstrate 6.5 TB/s on this path) vs
// round 9's nontemporal stores. nt loads kept (token row is single-use).
__global__ void mega_kernel(const u64* __restrict__ masks,
                            const float* __restrict__ probs,
                            const int* __restrict__ poffs,
                            const float* __restrict__ tokens,
                            float* __restrict__ out_rows,
                            float* __restrict__ out_probs,
                            float* __restrict__ out_idx) {
    int t = blockIdx.x;
    int c = t >> 8, tin = t & 255;
    int tid = threadIdx.x;

    // issue the row read early; consumed only at the stores
    const f32x4* sp = (const f32x4*)(tokens + (size_t)t * HID);
    f32x4 v0 = __builtin_nontemporal_load(sp + tid);
    f32x4 v1 = __builtin_nontemporal_load(sp + tid + 256);
    f32x4 v2 = __builtin_nontemporal_load(sp + tid + 512);
    f32x4 v3 = __builtin_nontemporal_load(sp + tid + 768);

    __shared__ u64 red[256];
    __shared__ int s_pos[TOPK];

    // this token's expert list (exactly TOPK set bits)
    u64 mk = masks[t];
    int e[TOPK];
    u64 tmp = mk;
#pragma unroll
    for (int j = 0; j < TOPK; ++j) {
        e[j] = tmp ? (__ffsll((long long)tmp) - 1) : 0;  // defensive
        tmp &= tmp - 1;
    }

    // packed contributions of earlier tokens in the chunk
    u64 contrib = 0;
    if (tid < tin) {
        u64 mi = masks[c * CHUNK + tid];
#pragma unroll
        for (int j = 0; j < TOPK; ++j)
            contrib |= ((mi >> e[j]) & 1ull) << (8 * j);
    }
    red[tid] = contrib;
    __syncthreads();
    for (int off = 128; off > 0; off >>= 1) {
        if (tid < off) red[tid] += red[tid + off];
        __syncthreads();
    }
    u64 ranks = red[0];

    if (tid < TOPK) {
        int ej = e[tid];
        int pos = poffs[ej * NCHUNK + c] + (int)((ranks >> (8 * tid)) & 0xff);
        if ((unsigned)pos >= OUTROW) pos = 0;            // defensive: never fault
        s_pos[tid] = pos;
        out_idx[pos] = (float)t;                         // exact for t < 2^24
        out_probs[pos] = probs[(size_t)t * NEXP + ej];
    }
    __syncthreads();

#pragma unroll
    for (int j = 0; j < TOPK; ++j) {
        int p = s_pos[j];
        f32x4* dp = (f32x4*)(out_rows + (size_t)p * HID);
        dp[tid]       = v0;
        dp[tid + 256] = v1;
        dp[tid + 512] = v2;
        dp[tid + 768] = v3;
    }
}

// ---------------------------------------------------------------------------
extern "C" void kernel_launch(void* const* d_in, const int* in_sizes, int n_in,
                              void* d_out, int out_size, void* d_ws, size_t ws_size,
                              hipStream_t stream) {
    const float* tokens = (const float*)d_in[0];
    const float* probs  = (const float*)d_in[1];
    const int*   map    = (const int*)d_in[2];

    float* out_rows  = (float*)d_out;                    // [OUTROW, HID]
    float* out_probs = out_rows + (size_t)OUTROW * HID;  // [OUTROW]
    float* out_idx   = out_probs + OUTROW;               // [OUTROW] float-coded ids

    // workspace: masks 64KB (u64, aligned first) + pcnt 8KB + poffs 8KB
    u64* masks = (u64*)d_ws;
    int* pcnt  = (int*)(masks + NTOK);
    int* poffs = pcnt + NPART;

    mask_count_kernel<<<NCHUNK, CHUNK, 0, stream>>>(map, masks, pcnt);
    scan_kernel<<<1, CHUNK, 0, stream>>>(pcnt, poffs);
    mega_kernel<<<NTOK, CHUNK, 0, stream>>>(masks, probs, poffs, tokens,
                                            out_rows, out_probs, out_idx);
}

// Round 11
// 271.179 us; speedup vs baseline: 1.0184x; 1.0184x over previous
//
#include <hip/hip_runtime.h>
#include <stdint.h>

// Problem constants (fixed by reference setup_inputs)
#define NTOK   8192
#define NEXP   64
#define HID    4096
#define TOPK   8
#define OUTROW 65536   // NTOK * TOPK
#define CHUNK  256     // tokens per chunk
#define NCHUNK 32      // NTOK / CHUNK
#define NPART  2048    // NEXP * NCHUNK, expert-major chunk-minor

typedef float f32x4 __attribute__((ext_vector_type(4)));
typedef unsigned long long u64;

// ---------------------------------------------------------------------------
// K1: per-token expert bitmasks + per-(expert,chunk) counts + PER-TOKEN PACKED
// RANKS. 32 blocks x 256 threads (one block per token chunk); map read exactly
// once (coalesced: lane = expert).
// Rank computation: lane e walks its wave's 64 tokens sequentially keeping a
// running exclusive count -> rnk[t][e] (ushort, 32 KB LDS); cross-wave prefix
// via wtot[4][64]. Each token then packs its 8 experts' ranks into one u64
// (byte per slot) -> tok_rank[t]. This removes ALL ranking work from mega.
__global__ void mask_rank_kernel(const int* __restrict__ map,
                                 u64* __restrict__ masks,
                                 u64* __restrict__ tok_rank,
                                 int* __restrict__ pcnt) {
    int c = blockIdx.x;
    int tid = threadIdx.x;
    int w = tid >> 6, lane = tid & 63;

    __shared__ u64 sm[CHUNK];                 // 2 KB
    __shared__ unsigned short rnk[CHUNK][NEXP]; // 32 KB
    __shared__ int wtot[4][NEXP];             // 1 KB

    // build masks via ballot (lane = expert; coalesced 256B rows)
    int t0 = c * CHUNK + w * 64;
#pragma unroll 8
    for (int i = 0; i < 64; ++i) {
        int v = map[(size_t)(t0 + i) * NEXP + lane];
        u64 bal = __ballot(v != 0);
        if (lane == 0) sm[w * 64 + i] = bal;
    }
    __syncthreads();

    // exclusive running count per expert over this wave's 64 tokens
    int cnt = 0;
#pragma unroll 8
    for (int i = 0; i < 64; ++i) {
        u64 mk = sm[w * 64 + i];              // broadcast LDS read
        rnk[w * 64 + i][lane] = (unsigned short)cnt;
        cnt += (int)((mk >> lane) & 1ull);
    }
    wtot[w][lane] = cnt;
    __syncthreads();

    // per-token: pack 8 expert ranks (+ cross-wave prefix) into u64
    u64 mk = sm[tid];
    masks[c * CHUNK + tid] = mk;
    int myw = tid >> 6;
    u64 tmp = mk;
    u64 packed = 0;
#pragma unroll
    for (int j = 0; j < TOPK; ++j) {
        int e = tmp ? (__ffsll((long long)tmp) - 1) : 0;  // defensive
        tmp &= tmp - 1;
        int r = rnk[tid][e];
        if (myw > 0) r += wtot[0][e];
        if (myw > 1) r += wtot[1][e];
        if (myw > 2) r += wtot[2][e];
        packed |= (u64)(r & 0xff) << (8 * j);
    }
    tok_rank[c * CHUNK + tid] = packed;

    // per-chunk expert counts
    if (tid < NEXP)
        pcnt[tid * NCHUNK + c] = wtot[0][tid] + wtot[1][tid] + wtot[2][tid] + wtot[3][tid];
}

// ---------------------------------------------------------------------------
// K2: exclusive prefix over the 2048 flat (expert-major, chunk-minor) counts.
__global__ void scan_kernel(const int* __restrict__ pcnt, int* __restrict__ poffs) {
    __shared__ int s[256];
    int tid = threadIdx.x;
    int v[8];
    int sum = 0;
#pragma unroll
    for (int i = 0; i < 8; ++i) { v[i] = pcnt[tid * 8 + i]; sum += v[i]; }
    s[tid] = sum;
    __syncthreads();
    for (int off = 1; off < 256; off <<= 1) {
        int x = (tid >= off) ? s[tid - off] : 0;
        __syncthreads();
        s[tid] += x;
        __syncthreads();
    }
    int base = (tid == 0) ? 0 : s[tid - 1];  // exclusive
#pragma unroll
    for (int i = 0; i < 8; ++i) { poffs[tid * 8 + i] = base; base += v[i]; }
}

// ---------------------------------------------------------------------------
// K3 (mega, pure streamer): one block per token. Positions come from two
// uniform u64 loads (mask + packed ranks) + 8 scalar poffs loads — no LDS,
// no barriers, no block-wide serialization before stores can issue.
// nt loads (row is single-use) + nt stores (round-10 A/B: nt beats plain by
// ~9 µs on this mixed stream). Value-major store order: the first 8 stores
// depend only on v0.
__global__ void mega_kernel(const u64* __restrict__ masks,
                            const u64* __restrict__ tok_rank,
                            const float* __restrict__ probs,
                            const int* __restrict__ poffs,
                            const float* __restrict__ tokens,
                            float* __restrict__ out_rows,
                            float* __restrict__ out_probs,
                            float* __restrict__ out_idx) {
    int t = blockIdx.x;
    int c = t >> 8;
    int tid = threadIdx.x;

    // issue the row read immediately
    const f32x4* sp = (const f32x4*)(tokens + (size_t)t * HID);
    f32x4 v0 = __builtin_nontemporal_load(sp + tid);
    f32x4 v1 = __builtin_nontemporal_load(sp + tid + 256);
    f32x4 v2 = __builtin_nontemporal_load(sp + tid + 512);
    f32x4 v3 = __builtin_nontemporal_load(sp + tid + 768);

    u64 mk = masks[t];       // wave-uniform
    u64 rk = tok_rank[t];    // wave-uniform

    f32x4* dp[TOPK];
    u64 tmp = mk;
#pragma unroll
    for (int j = 0; j < TOPK; ++j) {
        int e = tmp ? (__ffsll((long long)tmp) - 1) : 0;  // defensive
        tmp &= tmp - 1;
        int pos = poffs[e * NCHUNK + c] + (int)((rk >> (8 * j)) & 0xff);
        if ((unsigned)pos >= OUTROW) pos = 0;             // defensive: never fault
        dp[j] = (f32x4*)(out_rows + (size_t)pos * HID);
        if (tid == j) {
            out_idx[pos] = (float)t;                      // exact for t < 2^24
            out_probs[pos] = probs[(size_t)t * NEXP + e];
        }
    }

#pragma unroll
    for (int j = 0; j < TOPK; ++j) __builtin_nontemporal_store(v0, dp[j] + tid);
#pragma unroll
    for (int j = 0; j < TOPK; ++j) __builtin_nontemporal_store(v1, dp[j] + tid + 256);
#pragma unroll
    for (int j = 0; j < TOPK; ++j) __builtin_nontemporal_store(v2, dp[j] + tid + 512);
#pragma unroll
    for (int j = 0; j < TOPK; ++j) __builtin_nontemporal_store(v3, dp[j] + tid + 768);
}

// ---------------------------------------------------------------------------
extern "C" void kernel_launch(void* const* d_in, const int* in_sizes, int n_in,
                              void* d_out, int out_size, void* d_ws, size_t ws_size,
                              hipStream_t stream) {
    const float* tokens = (const float*)d_in[0];
    const float* probs  = (const float*)d_in[1];
    const int*   map    = (const int*)d_in[2];

    float* out_rows  = (float*)d_out;                    // [OUTROW, HID]
    float* out_probs = out_rows + (size_t)OUTROW * HID;  // [OUTROW]
    float* out_idx   = out_probs + OUTROW;               // [OUTROW] float-coded ids

    // workspace: masks 64KB + tok_rank 64KB + pcnt 8KB + poffs 8KB = 144KB
    u64* masks    = (u64*)d_ws;
    u64* tok_rank = masks + NTOK;
    int* pcnt     = (int*)(tok_rank + NTOK);
    int* poffs    = pcnt + NPART;

    mask_rank_kernel<<<NCHUNK, CHUNK, 0, stream>>>(map, masks, tok_rank, pcnt);
    scan_kernel<<<1, CHUNK, 0, stream>>>(pcnt, poffs);
    mega_kernel<<<NTOK, CHUNK, 0, stream>>>(masks, tok_rank, probs, poffs, tokens,
                                            out_rows, out_probs, out_idx);
}

// Round 12
// 267.266 us; speedup vs baseline: 1.0333x; 1.0146x over previous
//
#include <hip/hip_runtime.h>
#include <stdint.h>

// Problem constants (fixed by reference setup_inputs)
#define NTOK   8192
#define NEXP   64
#define HID    4096
#define TOPK   8
#define OUTROW 65536   // NTOK * TOPK
#define CHUNK  256     // tokens per chunk
#define NCHUNK 32      // NTOK / CHUNK
#define NPART  2048    // NEXP * NCHUNK, expert-major chunk-minor

typedef float f32x4 __attribute__((ext_vector_type(4)));
typedef unsigned long long u64;

// ---------------------------------------------------------------------------
// K1: per-token expert bitmasks + per-(expert,chunk) counts + per-token packed
// ranks. 32 blocks x 256 threads (one block per token chunk); map read exactly
// once (coalesced: lane = expert).
__global__ void mask_rank_kernel(const int* __restrict__ map,
                                 u64* __restrict__ masks,
                                 u64* __restrict__ tok_rank,
                                 int* __restrict__ pcnt) {
    int c = blockIdx.x;
    int tid = threadIdx.x;
    int w = tid >> 6, lane = tid & 63;

    __shared__ u64 sm[CHUNK];                   // 2 KB
    __shared__ unsigned short rnk[CHUNK][NEXP]; // 32 KB
    __shared__ int wtot[4][NEXP];               // 1 KB

    // build masks via ballot (lane = expert; coalesced 256B rows)
    int t0 = c * CHUNK + w * 64;
#pragma unroll 8
    for (int i = 0; i < 64; ++i) {
        int v = map[(size_t)(t0 + i) * NEXP + lane];
        u64 bal = __ballot(v != 0);
        if (lane == 0) sm[w * 64 + i] = bal;
    }
    __syncthreads();

    // exclusive running count per expert over this wave's 64 tokens
    int cnt = 0;
#pragma unroll 8
    for (int i = 0; i < 64; ++i) {
        u64 mk = sm[w * 64 + i];                // broadcast LDS read
        rnk[w * 64 + i][lane] = (unsigned short)cnt;
        cnt += (int)((mk >> lane) & 1ull);
    }
    wtot[w][lane] = cnt;
    __syncthreads();

    // per-token: pack 8 expert ranks (+ cross-wave prefix) into u64
    u64 mk = sm[tid];
    masks[c * CHUNK + tid] = mk;
    int myw = tid >> 6;
    u64 tmp = mk;
    u64 packed = 0;
#pragma unroll
    for (int j = 0; j < TOPK; ++j) {
        int e = tmp ? (__ffsll((long long)tmp) - 1) : 0;  // defensive
        tmp &= tmp - 1;
        int r = rnk[tid][e];
        if (myw > 0) r += wtot[0][e];
        if (myw > 1) r += wtot[1][e];
        if (myw > 2) r += wtot[2][e];
        packed |= (u64)(r & 0xff) << (8 * j);
    }
    tok_rank[c * CHUNK + tid] = packed;

    // per-chunk expert counts
    if (tid < NEXP)
        pcnt[tid * NCHUNK + c] = wtot[0][tid] + wtot[1][tid] + wtot[2][tid] + wtot[3][tid];
}

// ---------------------------------------------------------------------------
// K2: exclusive prefix over the 2048 flat (expert-major, chunk-minor) counts.
__global__ void scan_kernel(const int* __restrict__ pcnt, int* __restrict__ poffs) {
    __shared__ int s[256];
    int tid = threadIdx.x;
    int v[8];
    int sum = 0;
#pragma unroll
    for (int i = 0; i < 8; ++i) { v[i] = pcnt[tid * 8 + i]; sum += v[i]; }
    s[tid] = sum;
    __syncthreads();
    for (int off = 1; off < 256; off <<= 1) {
        int x = (tid >= off) ? s[tid - off] : 0;
        __syncthreads();
        s[tid] += x;
        __syncthreads();
    }
    int base = (tid == 0) ? 0 : s[tid - 1];  // exclusive
#pragma unroll
    for (int i = 0; i < 8; ++i) { poffs[tid * 8 + i] = base; base += v[i]; }
}

// ---------------------------------------------------------------------------
// K3 (mega): TWO blocks per token, each streams HALF the row (8 KB read,
// 8 x 8 KB writes). Finer granularity halves the per-block load->store
// dependency bubble and doubles independent streams per CU. Positions from
// two uniform u64 loads + 8 scalar poffs loads (no LDS, no barriers).
// nt loads (single-use row) + nt stores (R10 A/B: nt beats plain ~9 us).
// DESTINATION-MAJOR store order (R9 vs R11 A/B: finish each contiguous
// destination region before moving on -> better DRAM row locality).
__global__ void mega_kernel(const u64* __restrict__ masks,
                            const u64* __restrict__ tok_rank,
                            const float* __restrict__ probs,
                            const int* __restrict__ poffs,
                            const float* __restrict__ tokens,
                            float* __restrict__ out_rows,
                            float* __restrict__ out_probs,
                            float* __restrict__ out_idx) {
    int b = blockIdx.x;
    int t = b >> 1, h = b & 1;     // token, half
    int c = t >> 8;
    int tid = threadIdx.x;

    // issue the half-row read immediately (512 f32x4 per half)
    const f32x4* sp = (const f32x4*)(tokens + (size_t)t * HID) + h * 512;
    f32x4 v0 = __builtin_nontemporal_load(sp + tid);
    f32x4 v1 = __builtin_nontemporal_load(sp + tid + 256);

    u64 mk = tok_rank ? masks[t] : 0;  // wave-uniform
    mk = masks[t];
    u64 rk = tok_rank[t];              // wave-uniform

    f32x4* dp[TOPK];
    u64 tmp = mk;
#pragma unroll
    for (int j = 0; j < TOPK; ++j) {
        int e = tmp ? (__ffsll((long long)tmp) - 1) : 0;  // defensive
        tmp &= tmp - 1;
        int pos = poffs[e * NCHUNK + c] + (int)((rk >> (8 * j)) & 0xff);
        if ((unsigned)pos >= OUTROW) pos = 0;             // defensive: never fault
        dp[j] = (f32x4*)(out_rows + (size_t)pos * HID) + h * 512;
        if (h == 0 && tid == j) {
            out_idx[pos] = (float)t;                      // exact for t < 2^24
            out_probs[pos] = probs[(size_t)t * NEXP + e];
        }
    }

    // destination-major: complete each 8 KB region before the next
#pragma unroll
    for (int j = 0; j < TOPK; ++j) {
        __builtin_nontemporal_store(v0, dp[j] + tid);
        __builtin_nontemporal_store(v1, dp[j] + tid + 256);
    }
}

// ---------------------------------------------------------------------------
extern "C" void kernel_launch(void* const* d_in, const int* in_sizes, int n_in,
                              void* d_out, int out_size, void* d_ws, size_t ws_size,
                              hipStream_t stream) {
    const float* tokens = (const float*)d_in[0];
    const float* probs  = (const float*)d_in[1];
    const int*   map    = (const int*)d_in[2];

    float* out_rows  = (float*)d_out;                    // [OUTROW, HID]
    float* out_probs = out_rows + (size_t)OUTROW * HID;  // [OUTROW]
    float* out_idx   = out_probs + OUTROW;               // [OUTROW] float-coded ids

    // workspace: masks 64KB + tok_rank 64KB + pcnt 8KB + poffs 8KB = 144KB
    u64* masks    = (u64*)d_ws;
    u64* tok_rank = masks + NTOK;
    int* pcnt     = (int*)(tok_rank + NTOK);
    int* poffs    = pcnt + NPART;

    mask_rank_kernel<<<NCHUNK, CHUNK, 0, stream>>>(map, masks, tok_rank, pcnt);
    scan_kernel<<<1, CHUNK, 0, stream>>>(pcnt, poffs);
    mega_kernel<<<NTOK * 2, CHUNK, 0, stream>>>(masks, tok_rank, probs, poffs, tokens,
                                                out_rows, out_probs, out_idx);
}